// Round 4
// baseline (934.960 us; speedup 1.0000x reference)
//
#include <hip/hip_runtime.h>
#include <hip/hip_bf16.h>

typedef __attribute__((ext_vector_type(2))) float f32x2;
typedef __attribute__((ext_vector_type(8))) unsigned short ushort8;
typedef __attribute__((ext_vector_type(4))) unsigned short ushort4_t;

#define N_    4096
#define NSPLIT 16

__device__ inline float bf2f(unsigned short u){
  union{unsigned int i; float f;} c; c.i = ((unsigned int)u)<<16; return c.f;
}
__device__ inline unsigned short f2bf(float f){
  union{float f; unsigned int i;} c; c.f = f;
  unsigned int x = c.i;
  return (unsigned short)((x + 0x7fffu + ((x>>16)&1u)) >> 16);
}
__device__ inline float sigm(float s){ return 1.0f/(1.0f+__expf(-s)); }
__device__ inline f32x2 up2(unsigned int w){
  union{unsigned int i; float f;} lo, hi;
  lo.i = w<<16; hi.i = w & 0xffff0000u;
  f32x2 r; r.x = lo.f; r.y = hi.f; return r;
}

// block = 256 threads (4 waves). Full block sum.
__device__ inline float blkSum(float v, float* s4){
  v += __shfl_xor(v,1);  v += __shfl_xor(v,2);  v += __shfl_xor(v,4);
  v += __shfl_xor(v,8);  v += __shfl_xor(v,16); v += __shfl_xor(v,32);
  int lane = threadIdx.x & 63, w = threadIdx.x >> 6;
  __syncthreads();
  if (lane==0) s4[w] = v;
  __syncthreads();
  return s4[0]+s4[1]+s4[2]+s4[3];
}

// block = 1024 threads (16 waves). Full block sum.
__device__ inline float blkSum16(float v, float* s16){
  #pragma unroll
  for(int o=1;o<64;o<<=1) v += __shfl_xor(v,o);
  int lane = threadIdx.x & 63, w = threadIdx.x >> 6;
  __syncthreads();
  if (lane==0) s16[w] = v;
  __syncthreads();
  float r = 0.f;
  #pragma unroll
  for(int i=0;i<16;i++) r += s16[i];
  return r;
}

// ---------------- prep: transposed bf16 weights ---------------------------
// WvT[j][c] = Wv[c][j]; WqT[j][k] = Wq[k][j]; W1T[j][k] = W1[k][j];
// W2T[c][k] = W2[k][c].
__global__ __launch_bounds__(256) void k_prep(
    const float* __restrict__ Wv, const float* __restrict__ Wq,
    const float* __restrict__ W1, const float* __restrict__ W2,
    unsigned short* __restrict__ WvT, unsigned short* __restrict__ WqT,
    unsigned short* __restrict__ W1T, unsigned short* __restrict__ W2T){
  int idx = blockIdx.x*256 + threadIdx.x;          // 0 .. 262143
  if (idx < 65536){
    int j = idx>>8, c = idx&255;
    WvT[idx] = f2bf(Wv[c*256+j]);
    WqT[idx] = f2bf(Wq[c*256+j]);   // c plays role of k here
  }
  {
    int j = idx>>8, k = idx&255;     // W1T[j*256+k], j<1024
    W1T[idx] = f2bf(W1[k*1024+j]);
  }
  {
    int c = idx>>10, k = idx&1023;   // W2T[c*1024+k], c<256
    W2T[idx] = f2bf(W2[k*256+c]);
  }
}

// ---------------- init: rep0 = mu + exp(.5 lv)*eps ; q0 -> p0 -------------
__global__ __launch_bounds__(256) void k_init(
    const float* __restrict__ eps, const float* __restrict__ mu0,
    const float* __restrict__ lv0, const float* __restrict__ sg,
    const float* __restrict__ sb, const float* __restrict__ Wq,
    const float* __restrict__ Wk,
    float* __restrict__ rep, float* __restrict__ p_out){
  __shared__ float s4[4]; __shared__ float xq[256]; __shared__ float q_s[256];
  int b = blockIdx.x, c = threadIdx.x;
  float r0 = mu0[c] + __expf(0.5f*lv0[c]) * eps[b*256+c];
  rep[b*256+c] = r0;
  float mu = blkSum(r0, s4) * (1.0f/256.0f);
  float df = r0 - mu;
  float var = blkSum(df*df, s4) * (1.0f/256.0f);
  float rs = rsqrtf(var + 1e-5f);
  xq[c] = df*rs*sg[c] + sb[c];
  __syncthreads();
  float a0=0,a1=0,a2=0,a3=0;
  for(int k=0;k<256;k+=4){
    a0 += xq[k  ]*Wq[(k  )*256+c];
    a1 += xq[k+1]*Wq[(k+1)*256+c];
    a2 += xq[k+2]*Wq[(k+2)*256+c];
    a3 += xq[k+3]*Wq[(k+3)*256+c];
  }
  q_s[c] = a0+a1+a2+a3;
  __syncthreads();
  const float* wr = Wk + (size_t)c*256;
  #pragma unroll
  for(int h=0;h<4;h++){
    float acc=0.f;
    for(int d=0;d<64;d+=4){
      float4 wv = *reinterpret_cast<const float4*>(wr + h*64 + d);
      acc += wv.x*q_s[h*64+d] + wv.y*q_s[h*64+d+1]
           + wv.z*q_s[h*64+d+2] + wv.w*q_s[h*64+d+3];
    }
    p_out[b*1024 + h*256 + c] = 2.0f*acc;
  }
}

// ---------------- fused input-LN + attention pass 1 -----------------------
__global__ __launch_bounds__(256) void k_lnattn(
    const float* __restrict__ in, const float* __restrict__ g,
    const float* __restrict__ bln, const float* __restrict__ p,
    unsigned short* __restrict__ x,
    float* __restrict__ u_part, float* __restrict__ ws_part){
  int split = blockIdx.x;          // 0..15
  int b     = blockIdx.y;          // 0..127
  int tid = threadIdx.x, wid = tid>>6, lane = tid&63;
  const float* pb = p + (size_t)b*1024;
  float4 pp[4];
  #pragma unroll
  for(int h=0;h<4;h++) pp[h] = *reinterpret_cast<const float4*>(pb + h*256 + lane*4);
  float4 gg = reinterpret_cast<const float4*>(g)[lane];
  float4 bb = reinterpret_cast<const float4*>(bln)[lane];
  float4 u[4];
  #pragma unroll
  for(int h=0;h<4;h++){ u[h].x=0; u[h].y=0; u[h].z=0; u[h].w=0; }
  float wsum[4] = {0,0,0,0};
  const float* inb = in + ((size_t)b*N_ + split*256)*256;
  unsigned short* xb = x + ((size_t)b*N_ + split*256)*256;
  for(int it=0; it<64; ++it){
    int r = it*4 + wid;
    float4 v = *reinterpret_cast<const float4*>(inb + (size_t)r*256 + lane*4);
    float sm = v.x+v.y+v.z+v.w;
    float sq = v.x*v.x+v.y*v.y+v.z*v.z+v.w*v.w;
    #pragma unroll
    for(int o=1;o<64;o<<=1){ sm += __shfl_xor(sm,o); sq += __shfl_xor(sq,o); }
    float mu = sm*(1.0f/256.0f);
    float var = sq*(1.0f/256.0f) - mu*mu;
    float rs = rsqrtf(var + 1e-5f);
    float4 xv;
    xv.x = (v.x-mu)*rs*gg.x + bb.x;
    xv.y = (v.y-mu)*rs*gg.y + bb.y;
    xv.z = (v.z-mu)*rs*gg.z + bb.z;
    xv.w = (v.w-mu)*rs*gg.w + bb.w;
    ushort4_t o4;
    o4.x = f2bf(xv.x); o4.y = f2bf(xv.y); o4.z = f2bf(xv.z); o4.w = f2bf(xv.w);
    reinterpret_cast<ushort4_t*>(xb + (size_t)r*256)[lane] = o4;
    #pragma unroll
    for(int h=0;h<4;h++){
      float d = xv.x*pp[h].x + xv.y*pp[h].y + xv.z*pp[h].z + xv.w*pp[h].w;
      #pragma unroll
      for(int o=1;o<64;o<<=1) d += __shfl_xor(d,o);
      float w = sigm(d) + 1e-8f;
      wsum[h] += w;
      u[h].x += w*xv.x; u[h].y += w*xv.y; u[h].z += w*xv.z; u[h].w += w*xv.w;
    }
  }
  __shared__ float u_lds[4*4*256];   // [wid][h][c]
  __shared__ float ws_lds[4][4];
  #pragma unroll
  for(int h=0;h<4;h++)
    *reinterpret_cast<float4*>(&u_lds[wid*1024 + h*256 + lane*4]) = u[h];
  if (lane==0){
    #pragma unroll
    for(int h=0;h<4;h++) ws_lds[wid][h] = wsum[h];
  }
  __syncthreads();
  {
    int h = tid>>6, c0 = (tid&63)*4;
    float4 s0 = *reinterpret_cast<const float4*>(&u_lds[   0 + h*256 + c0]);
    float4 s1 = *reinterpret_cast<const float4*>(&u_lds[1024 + h*256 + c0]);
    float4 s2 = *reinterpret_cast<const float4*>(&u_lds[2048 + h*256 + c0]);
    float4 s3 = *reinterpret_cast<const float4*>(&u_lds[3072 + h*256 + c0]);
    float4 r; r.x=s0.x+s1.x+s2.x+s3.x; r.y=s0.y+s1.y+s2.y+s3.y;
    r.z=s0.z+s1.z+s2.z+s3.z; r.w=s0.w+s1.w+s2.w+s3.w;
    *reinterpret_cast<float4*>(u_part + (((size_t)split*128+b)*4+h)*256 + c0) = r;
  }
  if (tid<4)
    ws_part[((size_t)split*128+b)*4 + tid] =
      ws_lds[0][tid]+ws_lds[1][tid]+ws_lds[2][tid]+ws_lds[3][tid];
}

// ---------------- attention passes 2..4 on x (bf16) -----------------------
// rev=1: remap (split,b) -> (15-split, 127-b) so first-dispatched blocks
// read the data the previous pass touched last (L3 serpentine).
__global__ __launch_bounds__(256) void k_attn(
    const unsigned short* __restrict__ x, const float* __restrict__ p,
    float* __restrict__ u_part, float* __restrict__ ws_part,
    float* __restrict__ w_out, int write_w, int rev){
  int split = blockIdx.x;          // 0..15
  int b     = blockIdx.y;          // 0..127
  if (rev){ split = 15-split; b = 127-b; }
  int tid = threadIdx.x, wid = tid>>6, lane = tid&63;
  int rgrp = lane>>4, cl = lane&15;
  const float* pb = p + (size_t)b*1024;
  f32x2 pp[4][2][4];
  #pragma unroll
  for(int h=0;h<4;h++)
    #pragma unroll
    for(int qq=0;qq<2;qq++){
      const float4 a = *reinterpret_cast<const float4*>(pb + h*256 + qq*128 + cl*8);
      const float4 c = *reinterpret_cast<const float4*>(pb + h*256 + qq*128 + cl*8 + 4);
      pp[h][qq][0] = f32x2{a.x,a.y}; pp[h][qq][1] = f32x2{a.z,a.w};
      pp[h][qq][2] = f32x2{c.x,c.y}; pp[h][qq][3] = f32x2{c.z,c.w};
    }
  f32x2 u[4][2][4] = {};
  float wsum[4] = {0,0,0,0};
  const unsigned short* xb = x + (size_t)b*N_*256;
  for(int it=0; it<16; ++it){
    int n = (split<<8) + (it<<4) + (wid<<2) + rgrp;
    const unsigned short* xr = xb + (size_t)n*256;
    uint4 xa = *reinterpret_cast<const uint4*>(xr + cl*8);
    uint4 xc = *reinterpret_cast<const uint4*>(xr + 128 + cl*8);
    f32x2 xf[2][4];
    xf[0][0]=up2(xa.x); xf[0][1]=up2(xa.y); xf[0][2]=up2(xa.z); xf[0][3]=up2(xa.w);
    xf[1][0]=up2(xc.x); xf[1][1]=up2(xc.y); xf[1][2]=up2(xc.z); xf[1][3]=up2(xc.w);
    float w[4];
    #pragma unroll
    for(int h=0;h<4;h++){
      f32x2 d2 = xf[0][0]*pp[h][0][0];
      d2 += xf[0][1]*pp[h][0][1];
      d2 += xf[0][2]*pp[h][0][2];
      d2 += xf[0][3]*pp[h][0][3];
      d2 += xf[1][0]*pp[h][1][0];
      d2 += xf[1][1]*pp[h][1][1];
      d2 += xf[1][2]*pp[h][1][2];
      d2 += xf[1][3]*pp[h][1][3];
      float s = d2.x + d2.y;
      s += __shfl_xor(s,1); s += __shfl_xor(s,2);
      s += __shfl_xor(s,4); s += __shfl_xor(s,8);
      w[h] = sigm(s) + 1e-8f;
      wsum[h] += w[h];
    }
    #pragma unroll
    for(int h=0;h<4;h++){
      f32x2 w2; w2.x = w[h]; w2.y = w[h];
      #pragma unroll
      for(int qq=0;qq<2;qq++){
        u[h][qq][0] += w2*xf[qq][0];
        u[h][qq][1] += w2*xf[qq][1];
        u[h][qq][2] += w2*xf[qq][2];
        u[h][qq][3] += w2*xf[qq][3];
      }
    }
    if (write_w && cl==0){
      float4 wv; wv.x=w[0]; wv.y=w[1]; wv.z=w[2]; wv.w=w[3];
      *reinterpret_cast<float4*>(w_out + ((size_t)b*N_ + n)*4) = wv;
    }
  }
  #pragma unroll
  for(int h=0;h<4;h++){
    #pragma unroll
    for(int qq=0;qq<2;qq++)
      #pragma unroll
      for(int j=0;j<4;j++){
        f32x2 v = u[h][qq][j];
        v.x += __shfl_xor(v.x,16); v.y += __shfl_xor(v.y,16);
        v.x += __shfl_xor(v.x,32); v.y += __shfl_xor(v.y,32);
        u[h][qq][j] = v;
      }
    wsum[h] += __shfl_xor(wsum[h],16);
    wsum[h] += __shfl_xor(wsum[h],32);
  }
  __shared__ float u_lds[4*4*256];
  __shared__ float ws_lds[4][4];
  if (rgrp==0){   // lanes 0..15
    #pragma unroll
    for(int h=0;h<4;h++){
      #pragma unroll
      for(int qq=0;qq<2;qq++)
        #pragma unroll
        for(int j=0;j<4;j++){
          int c = qq*128 + cl*8 + j*2;
          u_lds[wid*1024 + h*256 + c    ] = u[h][qq][j].x;
          u_lds[wid*1024 + h*256 + c + 1] = u[h][qq][j].y;
        }
      if (lane==0) ws_lds[wid][h] = wsum[h];
    }
  }
  __syncthreads();
  {
    int h = tid>>6, c0 = (tid&63)*4;
    float4 s0 = *reinterpret_cast<const float4*>(u_lds +    0 + h*256 + c0);
    float4 s1 = *reinterpret_cast<const float4*>(u_lds + 1024 + h*256 + c0);
    float4 s2 = *reinterpret_cast<const float4*>(u_lds + 2048 + h*256 + c0);
    float4 s3 = *reinterpret_cast<const float4*>(u_lds + 3072 + h*256 + c0);
    float4 r; r.x=s0.x+s1.x+s2.x+s3.x; r.y=s0.y+s1.y+s2.y+s3.y;
    r.z=s0.z+s1.z+s2.z+s3.z; r.w=s0.w+s1.w+s2.w+s3.w;
    *reinterpret_cast<float4*>(u_part + (((size_t)split*128+b)*4+h)*256 + c0) = r;
  }
  if (tid<4)
    ws_part[((size_t)split*128+b)*4 + tid] =
      ws_lds[0][tid]+ws_lds[1][tid]+ws_lds[2][tid]+ws_lds[3][tid];
}

// ---------------- fused step: vectorized per-row dots ---------------------
__global__ __launch_bounds__(1024) void k_step(
    const float* __restrict__ u_part, const float* __restrict__ ws_part,
    const unsigned short* __restrict__ WvT, const float* __restrict__ Wih,
    const float* __restrict__ Whh, const float* __restrict__ bih,
    const float* __restrict__ bhh, const float* __restrict__ ln_rg,
    const float* __restrict__ ln_rb, const unsigned short* __restrict__ W1T,
    const unsigned short* __restrict__ W2T, const float* __restrict__ b2,
    const float* __restrict__ ln_sg, const float* __restrict__ ln_sb,
    const unsigned short* __restrict__ WqT, const float* __restrict__ Wk,
    float* __restrict__ rep, float* __restrict__ p_out,
    float* __restrict__ wsum_tot, float* __restrict__ out_rep, int last){
  __shared__ float u_s[1024];
  __shared__ float att_s[256];
  __shared__ float rep_s[256];
  __shared__ float ln_s[256];
  __shared__ float h1_s[1024];
  __shared__ float q_s[256];
  __shared__ float nw_s[256];
  __shared__ float gi_s[768], gh_s[768];
  __shared__ float red_a[1024];
  __shared__ float ws_s[4];
  __shared__ float s16[16];
  int b = blockIdx.x, t = threadIdx.x;
  int c = t & 255, s = t >> 8;
  // stage 1: sum u over splits; load rep
  {
    float acc = 0.f;
    #pragma unroll
    for(int sp=0;sp<NSPLIT;sp++)
      acc += u_part[((size_t)sp*128+b)*1024 + t];
    u_s[t] = acc;
    if (t < 4){
      float w=0.f;
      #pragma unroll
      for(int sp=0;sp<NSPLIT;sp++) w += ws_part[((size_t)sp*128+b)*4 + t];
      ws_s[t]=w; wsum_tot[b*4+t]=w;
    }
    if (t < 256) rep_s[t] = rep[b*256+t];
  }
  __syncthreads();
  // stage 2: att[j] = sum_cin u[h(j)][cin]*Wv[cin][j] / ws  (k-sliced x4)
  {
    const float* us = u_s + (c>>6)*256 + s*64;
    const unsigned short* wv = WvT + (size_t)c*256 + s*64;
    float a = 0.f;
    #pragma unroll
    for(int kk=0;kk<64;kk+=8){
      ushort8 w8 = *reinterpret_cast<const ushort8*>(wv + kk);
      #pragma unroll
      for(int j=0;j<8;j++) a += us[kk+j]*bf2f(w8[j]);
    }
    red_a[t] = a;
  }
  __syncthreads();
  if (t < 256) att_s[t] = (red_a[t]+red_a[256+t]+red_a[512+t]+red_a[768+t]) / ws_s[t>>6];
  __syncthreads();
  // stage 3: GRU, f32 original-layout weights, one output row per thread
  if (t < 768){
    const float* wi = Wih + (size_t)t*256;
    const float* wh = Whh + (size_t)t*256;
    float gi=0.f, gh=0.f;
    for(int k=0;k<256;k+=4){
      float4 wiv = *reinterpret_cast<const float4*>(wi + k);
      float4 whv = *reinterpret_cast<const float4*>(wh + k);
      gi += att_s[k]*wiv.x + att_s[k+1]*wiv.y + att_s[k+2]*wiv.z + att_s[k+3]*wiv.w;
      gh += rep_s[k]*whv.x + rep_s[k+1]*whv.y + rep_s[k+2]*whv.z + rep_s[k+3]*whv.w;
    }
    gi_s[t] = gi + bih[t];
    gh_s[t] = gh + bhh[t];
  }
  __syncthreads();
  if (t < 256){
    float rr = sigm(gi_s[t]     + gh_s[t]);
    float zz = sigm(gi_s[256+t] + gh_s[256+t]);
    float gg = tanhf(gi_s[512+t] + rr*gh_s[512+t]);
    nw_s[t] = (1.f-zz)*gg + zz*rep_s[t];
  }
  __syncthreads();
  // residual LN (all 1024 threads, each value counted 4x)
  {
    float v = nw_s[c];
    float mu = blkSum16(v, s16)*(1.0f/1024.0f);
    float df = v - mu;
    float var = blkSum16(df*df, s16)*(1.0f/1024.0f);
    float rs = rsqrtf(var+1e-5f);
    if (s==0) ln_s[c] = df*rs*ln_rg[c]+ln_rb[c];
    __syncthreads();
  }
  // stage 4: h1[j] = relu(ln . W1T[j])
  {
    const unsigned short* w1 = W1T + (size_t)t*256;
    float a = 0.f;
    #pragma unroll 4
    for(int k=0;k<256;k+=8){
      ushort8 w8 = *reinterpret_cast<const ushort8*>(w1 + k);
      #pragma unroll
      for(int j=0;j<8;j++) a += ln_s[k+j]*bf2f(w8[j]);
    }
    h1_s[t] = fmaxf(a, 0.f);
  }
  __syncthreads();
  // stage 5: mlp_out[c] = h1 . W2T[c]  (k-sliced x4 over 1024)
  {
    const unsigned short* w2 = W2T + (size_t)c*1024 + s*256;
    const float* hh = h1_s + s*256;
    float a = 0.f;
    #pragma unroll 4
    for(int k=0;k<256;k+=8){
      ushort8 w8 = *reinterpret_cast<const ushort8*>(w2 + k);
      #pragma unroll
      for(int j=0;j<8;j++) a += hh[k+j]*bf2f(w8[j]);
    }
    red_a[t] = a;
  }
  __syncthreads();
  if (t < 256){
    float rn = nw_s[t] + (red_a[t]+red_a[256+t]+red_a[512+t]+red_a[768+t]) + b2[t];
    rep[b*256+t] = rn;
    if (last) out_rep[b*256+t] = rn;
    nw_s[t] = rn;
  }
  __syncthreads();
  if (last) return;
  // slot-LN
  {
    float v = nw_s[c];
    float mu = blkSum16(v, s16)*(1.0f/1024.0f);
    float df = v - mu;
    float var = blkSum16(df*df, s16)*(1.0f/1024.0f);
    float rs = rsqrtf(var+1e-5f);
    if (s==0) ln_s[c] = df*rs*ln_sg[c]+ln_sb[c];
    __syncthreads();
  }
  // stage 6: q[j] = ln . WqT[j]  (k-sliced x4)
  {
    const unsigned short* wq = WqT + (size_t)c*256 + s*64;
    const float* ls = ln_s + s*64;
    float a = 0.f;
    #pragma unroll
    for(int kk=0;kk<64;kk+=8){
      ushort8 w8 = *reinterpret_cast<const ushort8*>(wq + kk);
      #pragma unroll
      for(int j=0;j<8;j++) a += ls[kk+j]*bf2f(w8[j]);
    }
    red_a[t] = a;
  }
  __syncthreads();
  if (t < 256) q_s[t] = red_a[t]+red_a[256+t]+red_a[512+t]+red_a[768+t];
  __syncthreads();
  // stage 7: p[h=s][c] = 2 * Wk[c][h*64..] . q[h*64..]
  {
    const float* wr = Wk + (size_t)c*256 + s*64;
    float a = 0.f;
    #pragma unroll
    for(int d=0;d<64;d+=4){
      float4 wv = *reinterpret_cast<const float4*>(wr + d);
      a += wv.x*q_s[s*64+d] + wv.y*q_s[s*64+d+1]
         + wv.z*q_s[s*64+d+2] + wv.w*q_s[s*64+d+3];
    }
    p_out[b*1024 + s*256 + c] = 2.0f*a;
  }
}

// ---------------- final w output ------------------------------------------
__global__ __launch_bounds__(256) void k_wout(
    const float* __restrict__ w_buf, const float* __restrict__ wsum_tot,
    float* __restrict__ out){
  int idx = blockIdx.x*256 + threadIdx.x;     // 0..524287
  int b = idx>>12;
  float4 w4 = *reinterpret_cast<const float4*>(w_buf + (size_t)idx*4);
  out[idx] = w4.x/wsum_tot[b*4+0] + w4.y/wsum_tot[b*4+1]
           + w4.z/wsum_tot[b*4+2] + w4.w/wsum_tot[b*4+3];
}

extern "C" void kernel_launch(void* const* d_in, const int* in_sizes, int n_in,
                              void* d_out, int out_size, void* d_ws, size_t ws_size,
                              hipStream_t stream){
  const float* inputs  = (const float*)d_in[0];
  const float* eps     = (const float*)d_in[1];
  const float* init_mu = (const float*)d_in[2];
  const float* init_lv = (const float*)d_in[3];
  const float* Wk      = (const float*)d_in[4];
  const float* Wv      = (const float*)d_in[5];
  const float* Wq      = (const float*)d_in[6];
  const float* ln_in_g = (const float*)d_in[7];
  const float* ln_in_b = (const float*)d_in[8];
  const float* ln_sg   = (const float*)d_in[9];
  const float* ln_sb   = (const float*)d_in[10];
  const float* ln_rg   = (const float*)d_in[11];
  const float* ln_rb   = (const float*)d_in[12];
  const float* Wih     = (const float*)d_in[13];
  const float* Whh     = (const float*)d_in[14];
  const float* bih     = (const float*)d_in[15];
  const float* bhh     = (const float*)d_in[16];
  const float* W1      = (const float*)d_in[17];
  const float* W2      = (const float*)d_in[18];
  const float* b2      = (const float*)d_in[19];

  char* ws = (char*)d_ws;
  size_t off = 0;
  auto alloc = [&](size_t bytes)->void*{
    void* p = ws + off; off += (bytes + 255) & ~(size_t)255; return p;
  };
  unsigned short* x    = (unsigned short*)alloc((size_t)128*N_*256*2);
  unsigned short* WvT  = (unsigned short*)alloc(256*256*2);
  unsigned short* WqT  = (unsigned short*)alloc(256*256*2);
  unsigned short* W1T  = (unsigned short*)alloc(1024*256*2);
  unsigned short* W2T  = (unsigned short*)alloc(256*1024*2);
  float* p_buf    = (float*)alloc((size_t)128*1024*4);
  float* u_part   = (float*)alloc((size_t)NSPLIT*128*1024*4);
  float* ws_part  = (float*)alloc((size_t)NSPLIT*128*4*4);
  float* wsum_tot = (float*)alloc(512*4);
  float* rep      = (float*)alloc(128*256*4);
  float* w_buf    = (float*)alloc((size_t)128*N_*4*4);

  float* out_rep = (float*)d_out;
  float* out_w   = out_rep + 128*256;

  k_prep<<<1024,256,0,stream>>>(Wv, Wq, W1, W2, WvT, WqT, W1T, W2T);
  k_init<<<128,256,0,stream>>>(eps, init_mu, init_lv, ln_sg, ln_sb, Wq, Wk, rep, p_buf);
  k_lnattn<<<dim3(NSPLIT,128),256,0,stream>>>(inputs, ln_in_g, ln_in_b, p_buf,
                                              x, u_part, ws_part);
  for(int t=0;t<4;t++){
    int last = (t==3) ? 1 : 0;
    if (t>0)
      k_attn<<<dim3(NSPLIT,128),256,0,stream>>>(x, p_buf, u_part, ws_part,
                                                w_buf, last, t&1);
    k_step<<<128,1024,0,stream>>>(u_part, ws_part, WvT, Wih, Whh, bih, bhh,
                                  ln_rg, ln_rb, W1T, W2T, b2, ln_sg, ln_sb,
                                  WqT, Wk, rep, p_buf, wsum_tot, out_rep, last);
  }
  k_wout<<<2048,256,0,stream>>>(w_buf, wsum_tot, out_w);
}

// Round 5
// 614.493 us; speedup vs baseline: 1.5215x; 1.5215x over previous
//
#include <hip/hip_runtime.h>
#include <hip/hip_bf16.h>

typedef __attribute__((ext_vector_type(2))) float f32x2;
typedef __attribute__((ext_vector_type(8))) unsigned short ushort8;
typedef __attribute__((ext_vector_type(4))) unsigned short ushort4_t;

#define N_    4096

__device__ inline float bf2f(unsigned short u){
  union{unsigned int i; float f;} c; c.i = ((unsigned int)u)<<16; return c.f;
}
__device__ inline unsigned short f2bf(float f){
  union{float f; unsigned int i;} c; c.f = f;
  unsigned int x = c.i;
  return (unsigned short)((x + 0x7fffu + ((x>>16)&1u)) >> 16);
}
__device__ inline float sigm(float s){ return 1.0f/(1.0f+__expf(-s)); }
__device__ inline f32x2 up2(unsigned int w){
  union{unsigned int i; float f;} lo, hi;
  lo.i = w<<16; hi.i = w & 0xffff0000u;
  f32x2 r; r.x = lo.f; r.y = hi.f; return r;
}

// block = 256 threads (4 waves). Full block sum.
__device__ inline float blkSum(float v, float* s4){
  v += __shfl_xor(v,1);  v += __shfl_xor(v,2);  v += __shfl_xor(v,4);
  v += __shfl_xor(v,8);  v += __shfl_xor(v,16); v += __shfl_xor(v,32);
  int lane = threadIdx.x & 63, w = threadIdx.x >> 6;
  __syncthreads();
  if (lane==0) s4[w] = v;
  __syncthreads();
  return s4[0]+s4[1]+s4[2]+s4[3];
}

// block = 1024 threads (16 waves). Full block sum.
__device__ inline float blkSum16(float v, float* s16){
  #pragma unroll
  for(int o=1;o<64;o<<=1) v += __shfl_xor(v,o);
  int lane = threadIdx.x & 63, w = threadIdx.x >> 6;
  __syncthreads();
  if (lane==0) s16[w] = v;
  __syncthreads();
  float r = 0.f;
  #pragma unroll
  for(int i=0;i<16;i++) r += s16[i];
  return r;
}

// ---------------- prep: packed-k bf16 weights -----------------------------
// All packed layouts: Wp[(pk*J + j)*4 + i] = W_col[j][4*pk+i]; thread j loads
// ushort4 at 8B lane stride (coalesced) and gets 4 k-terms.
__global__ __launch_bounds__(256) void k_prep(
    const float* __restrict__ Wv, const float* __restrict__ Wih,
    const float* __restrict__ Whh, const float* __restrict__ W1,
    const float* __restrict__ W2, const float* __restrict__ Wq,
    const float* __restrict__ Wk,
    unsigned short* __restrict__ Wvp, unsigned short* __restrict__ Wip,
    unsigned short* __restrict__ Whp, unsigned short* __restrict__ W1p,
    unsigned short* __restrict__ W2p, unsigned short* __restrict__ Wqp,
    unsigned short* __restrict__ Wkp){
  int e = blockIdx.x*256 + threadIdx.x;          // 0 .. 262143
  { // Wvp / Wqp: J=256, K=256  (att[j] = sum_k u[k]*Wv[k][j])
    if (e < 65536){
      int i = e&3, j = (e>>2)&255, pk = e>>10;
      Wvp[e] = f2bf(Wv[(4*pk+i)*256 + j]);
      Wqp[e] = f2bf(Wq[(4*pk+i)*256 + j]);
    }
  }
  { // Wip / Whp: J=768, K=256  (gi[j] = sum_k a[k]*Wih[j][k], Wih row-major [768][256])
    if (e < 196608){
      int i = e&3, j2 = e>>2;
      int j = j2 % 768, pk = j2 / 768;
      Wip[e] = f2bf(Wih[j*256 + 4*pk+i]);
      Whp[e] = f2bf(Whh[j*256 + 4*pk+i]);
    }
  }
  { // W1p: J=1024, K=256
    int i = e&3, j = (e>>2)&1023, pk = e>>12;
    W1p[e] = f2bf(W1[(4*pk+i)*1024 + j]);
  }
  { // W2p: J=256, K=1024
    int i = e&3, j = (e>>2)&255, pk = e>>10;
    W2p[e] = f2bf(W2[(4*pk+i)*256 + j]);
  }
  { // Wkp: J=1024 (hc), K=64 (d); p[h][c] = 2*sum_d q[h*64+d]*Wk[c][h*64+d]
    if (e < 65536){
      int i = e&3, hc = (e>>2)&1023, pd = e>>12;
      int h = hc>>8, c = hc&255;
      Wkp[e] = f2bf(Wk[c*256 + h*64 + 4*pd+i]);
    }
  }
}

// ---------------- init: rep0 = mu + exp(.5 lv)*eps ; q0 -> p0 -------------
__global__ __launch_bounds__(256) void k_init(
    const float* __restrict__ eps, const float* __restrict__ mu0,
    const float* __restrict__ lv0, const float* __restrict__ sg,
    const float* __restrict__ sb, const float* __restrict__ Wq,
    const unsigned short* __restrict__ Wkp,
    float* __restrict__ rep, float* __restrict__ p_out){
  __shared__ float s4[4]; __shared__ float xq[256]; __shared__ float q_s[256];
  int b = blockIdx.x, c = threadIdx.x;
  float r0 = mu0[c] + __expf(0.5f*lv0[c]) * eps[b*256+c];
  rep[b*256+c] = r0;
  float mu = blkSum(r0, s4) * (1.0f/256.0f);
  float df = r0 - mu;
  float var = blkSum(df*df, s4) * (1.0f/256.0f);
  float rs = rsqrtf(var + 1e-5f);
  xq[c] = df*rs*sg[c] + sb[c];
  __syncthreads();
  float a0=0,a1=0,a2=0,a3=0;
  for(int k=0;k<256;k+=4){
    a0 += xq[k  ]*Wq[(k  )*256+c];
    a1 += xq[k+1]*Wq[(k+1)*256+c];
    a2 += xq[k+2]*Wq[(k+2)*256+c];
    a3 += xq[k+3]*Wq[(k+3)*256+c];
  }
  q_s[c] = a0+a1+a2+a3;
  __syncthreads();
  #pragma unroll
  for(int h=0;h<4;h++){
    float acc = 0.f;
    for(int pd=0;pd<16;pd++){
      ushort4_t w4 = *reinterpret_cast<const ushort4_t*>(Wkp + ((size_t)pd*1024 + h*256 + c)*4);
      acc += bf2f(w4.x)*q_s[h*64+4*pd  ] + bf2f(w4.y)*q_s[h*64+4*pd+1]
           + bf2f(w4.z)*q_s[h*64+4*pd+2] + bf2f(w4.w)*q_s[h*64+4*pd+3];
    }
    p_out[b*1024 + h*256 + c] = 2.0f*acc;
  }
}

// ---------------- fused input-LN + attention pass 1 -----------------------
// grid (2,128) x 1024 thr. Block handles 2048 rows of batch b; 32 lanes/row.
__global__ __launch_bounds__(1024) void k_lnattn(
    const float* __restrict__ in, const float* __restrict__ g,
    const float* __restrict__ bln, const float* __restrict__ p,
    unsigned short* __restrict__ x,
    float* __restrict__ u_part, float* __restrict__ ws_part){
  __shared__ float u_red[8][1024];
  __shared__ float ws_red[16][4];
  int split = blockIdx.x, b = blockIdx.y;
  int tid = threadIdx.x, wid = tid>>6, lane = tid&63;
  int grp = tid>>5, cl = tid&31;       // grp 0..31, lane-in-row 0..31
  const float* pb = p + (size_t)b*1024;
  float pp[4][8];
  #pragma unroll
  for(int h=0;h<4;h++){
    float4 pa = *reinterpret_cast<const float4*>(pb + h*256 + cl*8);
    float4 pc = *reinterpret_cast<const float4*>(pb + h*256 + cl*8 + 4);
    pp[h][0]=pa.x; pp[h][1]=pa.y; pp[h][2]=pa.z; pp[h][3]=pa.w;
    pp[h][4]=pc.x; pp[h][5]=pc.y; pp[h][6]=pc.z; pp[h][7]=pc.w;
  }
  float gg[8], bb[8];
  {
    float4 a = *reinterpret_cast<const float4*>(g + cl*8);
    float4 c = *reinterpret_cast<const float4*>(g + cl*8 + 4);
    gg[0]=a.x; gg[1]=a.y; gg[2]=a.z; gg[3]=a.w; gg[4]=c.x; gg[5]=c.y; gg[6]=c.z; gg[7]=c.w;
    a = *reinterpret_cast<const float4*>(bln + cl*8);
    c = *reinterpret_cast<const float4*>(bln + cl*8 + 4);
    bb[0]=a.x; bb[1]=a.y; bb[2]=a.z; bb[3]=a.w; bb[4]=c.x; bb[5]=c.y; bb[6]=c.z; bb[7]=c.w;
  }
  float u[4][8] = {};
  float wsum[4] = {0,0,0,0};
  const float* inb = in + ((size_t)b*N_ + split*2048)*256;
  unsigned short* xb = x + ((size_t)b*N_ + split*2048)*256;
  for(int it=0; it<64; ++it){
    int r = it*32 + grp;
    float xv[8];
    {
      float4 a = *reinterpret_cast<const float4*>(inb + (size_t)r*256 + cl*8);
      float4 c = *reinterpret_cast<const float4*>(inb + (size_t)r*256 + cl*8 + 4);
      xv[0]=a.x; xv[1]=a.y; xv[2]=a.z; xv[3]=a.w; xv[4]=c.x; xv[5]=c.y; xv[6]=c.z; xv[7]=c.w;
    }
    float sm=0.f, sq=0.f;
    #pragma unroll
    for(int j=0;j<8;j++){ sm += xv[j]; sq += xv[j]*xv[j]; }
    #pragma unroll
    for(int o=1;o<32;o<<=1){ sm += __shfl_xor(sm,o); sq += __shfl_xor(sq,o); }
    float mu = sm*(1.0f/256.0f);
    float var = sq*(1.0f/256.0f) - mu*mu;
    float rs = rsqrtf(var + 1e-5f);
    ushort8 o8;
    #pragma unroll
    for(int j=0;j<8;j++){
      xv[j] = (xv[j]-mu)*rs*gg[j] + bb[j];
      o8[j] = f2bf(xv[j]);
    }
    *reinterpret_cast<ushort8*>(xb + (size_t)r*256 + cl*8) = o8;
    #pragma unroll
    for(int h=0;h<4;h++){
      float d = 0.f;
      #pragma unroll
      for(int j=0;j<8;j++) d += xv[j]*pp[h][j];
      #pragma unroll
      for(int o=1;o<32;o<<=1) d += __shfl_xor(d,o);
      float w = sigm(d) + 1e-8f;
      wsum[h] += w;
      #pragma unroll
      for(int j=0;j<8;j++) u[h][j] += w*xv[j];
    }
  }
  // cross-group (xor 32) reduce
  #pragma unroll
  for(int h=0;h<4;h++){
    #pragma unroll
    for(int j=0;j<8;j++) u[h][j] += __shfl_xor(u[h][j],32);
    wsum[h] += __shfl_xor(wsum[h],32);
  }
  if (wid < 8 && lane < 32){
    #pragma unroll
    for(int h=0;h<4;h++){
      float4 a; a.x=u[h][0]; a.y=u[h][1]; a.z=u[h][2]; a.w=u[h][3];
      float4 c; c.x=u[h][4]; c.y=u[h][5]; c.z=u[h][6]; c.w=u[h][7];
      *reinterpret_cast<float4*>(&u_red[wid][h*256 + cl*8    ]) = a;
      *reinterpret_cast<float4*>(&u_red[wid][h*256 + cl*8 + 4]) = c;
    }
  }
  if (lane==0){
    #pragma unroll
    for(int h=0;h<4;h++) ws_red[wid][h] = wsum[h];
  }
  __syncthreads();
  if (wid >= 8 && lane < 32){
    #pragma unroll
    for(int h=0;h<4;h++){
      float4 a = *reinterpret_cast<const float4*>(&u_red[wid-8][h*256 + cl*8]);
      float4 c = *reinterpret_cast<const float4*>(&u_red[wid-8][h*256 + cl*8 + 4]);
      a.x+=u[h][0]; a.y+=u[h][1]; a.z+=u[h][2]; a.w+=u[h][3];
      c.x+=u[h][4]; c.y+=u[h][5]; c.z+=u[h][6]; c.w+=u[h][7];
      *reinterpret_cast<float4*>(&u_red[wid-8][h*256 + cl*8    ]) = a;
      *reinterpret_cast<float4*>(&u_red[wid-8][h*256 + cl*8 + 4]) = c;
    }
  }
  __syncthreads();
  {
    float s = 0.f;
    #pragma unroll
    for(int w=0;w<8;w++) s += u_red[w][tid];
    u_part[((size_t)split*128 + b)*1024 + tid] = s;
  }
  if (tid < 4){
    float s = 0.f;
    #pragma unroll
    for(int w=0;w<16;w++) s += ws_red[w][tid];
    ws_part[((size_t)split*128 + b)*4 + tid] = s;
  }
}

// ---------------- fused step + attention pass -----------------------------
// grid (2,128) x 1024 thr. Phase S: step for this b (redundant x2, coalesced
// packed-k GEMVs, weights L2-resident). Phase A: attention over 2048 rows.
__global__ __launch_bounds__(1024) void k_attnstep(
    const unsigned short* __restrict__ x,
    const float* __restrict__ u_in, const float* __restrict__ ws_in,
    const float* __restrict__ rep_in, float* __restrict__ rep_out,
    const unsigned short* __restrict__ Wvp, const unsigned short* __restrict__ Wip,
    const unsigned short* __restrict__ Whp, const float* __restrict__ bih,
    const float* __restrict__ bhh, const float* __restrict__ ln_rg,
    const float* __restrict__ ln_rb, const unsigned short* __restrict__ W1p,
    const unsigned short* __restrict__ W2p, const float* __restrict__ b2,
    const float* __restrict__ ln_sg, const float* __restrict__ ln_sb,
    const unsigned short* __restrict__ Wqp, const unsigned short* __restrict__ Wkp,
    float* __restrict__ u_out, float* __restrict__ ws_out,
    float* __restrict__ w_buf, int write_w){
  __shared__ float u_s[1024];
  __shared__ float att_s[256], rep_s[256], ln_s[256], nw_s[256], q_s[256];
  __shared__ float gi_s[768], gh_s[768];
  __shared__ float h1_s[1024], p_s[1024], red_a[1024];
  __shared__ float ws_s[4]; __shared__ float s16[16];
  __shared__ float u_red[8][1024];
  __shared__ float ws_red[16][4];
  int split = blockIdx.x, b = blockIdx.y;
  int tid = threadIdx.x;
  int c = tid & 255, s = tid >> 8;
  // ---- phase S ----
  {
    u_s[tid] = u_in[(size_t)b*1024 + tid] + u_in[((size_t)128 + b)*1024 + tid];
    if (tid < 4) ws_s[tid] = ws_in[b*4 + tid] + ws_in[(128 + b)*4 + tid];
    if (tid < 256) rep_s[tid] = rep_in[b*256 + tid];
  }
  __syncthreads();
  { // att partial: j=c, k-slice s (64 k = 16 packs)
    const float* uh = u_s + (c>>6)*256;
    float a = 0.f;
    for(int pk=s*16; pk<s*16+16; ++pk){
      ushort4_t w4 = *reinterpret_cast<const ushort4_t*>(Wvp + ((size_t)pk*256 + c)*4);
      a += bf2f(w4.x)*uh[4*pk] + bf2f(w4.y)*uh[4*pk+1]
         + bf2f(w4.z)*uh[4*pk+2] + bf2f(w4.w)*uh[4*pk+3];
    }
    red_a[tid] = a;
  }
  __syncthreads();
  if (tid < 256) att_s[tid] = (red_a[tid]+red_a[256+tid]+red_a[512+tid]+red_a[768+tid]) / ws_s[tid>>6];
  __syncthreads();
  if (tid < 768){ // GRU rows, full K, packed
    float gi=0.f, gh=0.f;
    for(int pk=0;pk<64;++pk){
      ushort4_t wi = *reinterpret_cast<const ushort4_t*>(Wip + ((size_t)pk*768 + tid)*4);
      ushort4_t wh = *reinterpret_cast<const ushort4_t*>(Whp + ((size_t)pk*768 + tid)*4);
      gi += bf2f(wi.x)*att_s[4*pk] + bf2f(wi.y)*att_s[4*pk+1]
          + bf2f(wi.z)*att_s[4*pk+2] + bf2f(wi.w)*att_s[4*pk+3];
      gh += bf2f(wh.x)*rep_s[4*pk] + bf2f(wh.y)*rep_s[4*pk+1]
          + bf2f(wh.z)*rep_s[4*pk+2] + bf2f(wh.w)*rep_s[4*pk+3];
    }
    gi_s[tid] = gi + bih[tid];
    gh_s[tid] = gh + bhh[tid];
  }
  __syncthreads();
  if (tid < 256){
    float rr = sigm(gi_s[tid]     + gh_s[tid]);
    float zz = sigm(gi_s[256+tid] + gh_s[256+tid]);
    float t3 = tanhf(gi_s[512+tid] + rr*gh_s[512+tid]);
    nw_s[tid] = (1.f-zz)*t3 + zz*rep_s[tid];
  }
  __syncthreads();
  { // residual LN
    float v = nw_s[c];
    float mu = blkSum16(v, s16)*(1.0f/1024.0f);
    float df = v - mu;
    float var = blkSum16(df*df, s16)*(1.0f/1024.0f);
    float rs = rsqrtf(var+1e-5f);
    if (s==0) ln_s[c] = df*rs*ln_rg[c]+ln_rb[c];
  }
  __syncthreads();
  { // W1 row per thread
    float a = 0.f;
    for(int pk=0;pk<64;++pk){
      ushort4_t w4 = *reinterpret_cast<const ushort4_t*>(W1p + ((size_t)pk*1024 + tid)*4);
      a += bf2f(w4.x)*ln_s[4*pk] + bf2f(w4.y)*ln_s[4*pk+1]
         + bf2f(w4.z)*ln_s[4*pk+2] + bf2f(w4.w)*ln_s[4*pk+3];
    }
    h1_s[tid] = fmaxf(a, 0.f);
  }
  __syncthreads();
  { // W2: j=c, k-slice s (256 k = 64 packs)
    float a = 0.f;
    for(int pk=s*64; pk<s*64+64; ++pk){
      ushort4_t w4 = *reinterpret_cast<const ushort4_t*>(W2p + ((size_t)pk*256 + c)*4);
      a += bf2f(w4.x)*h1_s[4*pk] + bf2f(w4.y)*h1_s[4*pk+1]
         + bf2f(w4.z)*h1_s[4*pk+2] + bf2f(w4.w)*h1_s[4*pk+3];
    }
    red_a[tid] = a;
  }
  __syncthreads();
  if (tid < 256){
    float rn = nw_s[tid] + (red_a[tid]+red_a[256+tid]+red_a[512+tid]+red_a[768+tid]) + b2[tid];
    nw_s[tid] = rn;
    if (split==0) rep_out[b*256+tid] = rn;
  }
  __syncthreads();
  { // slot LN
    float v = nw_s[c];
    float mu = blkSum16(v, s16)*(1.0f/1024.0f);
    float df = v - mu;
    float var = blkSum16(df*df, s16)*(1.0f/1024.0f);
    float rs = rsqrtf(var+1e-5f);
    if (s==0) ln_s[c] = df*rs*ln_sg[c]+ln_sb[c];
  }
  __syncthreads();
  { // q: j=c, k-slice s
    float a = 0.f;
    for(int pk=s*16; pk<s*16+16; ++pk){
      ushort4_t w4 = *reinterpret_cast<const ushort4_t*>(Wqp + ((size_t)pk*256 + c)*4);
      a += bf2f(w4.x)*ln_s[4*pk] + bf2f(w4.y)*ln_s[4*pk+1]
         + bf2f(w4.z)*ln_s[4*pk+2] + bf2f(w4.w)*ln_s[4*pk+3];
    }
    red_a[tid] = a;
  }
  __syncthreads();
  if (tid < 256) q_s[tid] = red_a[tid]+red_a[256+tid]+red_a[512+tid]+red_a[768+tid];
  __syncthreads();
  { // p: one (h,c) per thread
    int h = tid>>8;
    float a = 0.f;
    for(int pd=0;pd<16;++pd){
      ushort4_t w4 = *reinterpret_cast<const ushort4_t*>(Wkp + ((size_t)pd*1024 + tid)*4);
      a += bf2f(w4.x)*q_s[h*64+4*pd] + bf2f(w4.y)*q_s[h*64+4*pd+1]
         + bf2f(w4.z)*q_s[h*64+4*pd+2] + bf2f(w4.w)*q_s[h*64+4*pd+3];
    }
    p_s[tid] = 2.0f*a;
  }
  __syncthreads();
  // ---- phase A ----
  int wid = tid>>6, lane = tid&63;
  int grp = tid>>5, cl = tid&31;
  f32x2 pp2[4][4];
  #pragma unroll
  for(int h=0;h<4;h++)
    #pragma unroll
    for(int j2=0;j2<4;j2++){
      pp2[h][j2].x = p_s[h*256 + cl*8 + j2*2];
      pp2[h][j2].y = p_s[h*256 + cl*8 + j2*2 + 1];
    }
  f32x2 u2[4][4] = {};
  float wsum[4] = {0,0,0,0};
  const unsigned short* xb = x + ((size_t)b*N_ + split*2048)*256;
  for(int it=0; it<64; ++it){
    int r = it*32 + grp;
    uint4 xa = *reinterpret_cast<const uint4*>(xb + (size_t)r*256 + cl*8);
    f32x2 xf[4];
    xf[0]=up2(xa.x); xf[1]=up2(xa.y); xf[2]=up2(xa.z); xf[3]=up2(xa.w);
    float w[4];
    #pragma unroll
    for(int h=0;h<4;h++){
      f32x2 d2 = xf[0]*pp2[h][0];
      d2 += xf[1]*pp2[h][1];
      d2 += xf[2]*pp2[h][2];
      d2 += xf[3]*pp2[h][3];
      float d = d2.x + d2.y;
      #pragma unroll
      for(int o=1;o<32;o<<=1) d += __shfl_xor(d,o);
      w[h] = sigm(d) + 1e-8f;
      wsum[h] += w[h];
    }
    #pragma unroll
    for(int h=0;h<4;h++){
      f32x2 w2; w2.x = w[h]; w2.y = w[h];
      #pragma unroll
      for(int j2=0;j2<4;j2++) u2[h][j2] += w2*xf[j2];
    }
    if (write_w && cl==0){
      float4 wv; wv.x=w[0]; wv.y=w[1]; wv.z=w[2]; wv.w=w[3];
      *reinterpret_cast<float4*>(w_buf + ((size_t)b*N_ + split*2048 + r)*4) = wv;
    }
  }
  #pragma unroll
  for(int h=0;h<4;h++){
    #pragma unroll
    for(int j2=0;j2<4;j2++){
      u2[h][j2].x += __shfl_xor(u2[h][j2].x,32);
      u2[h][j2].y += __shfl_xor(u2[h][j2].y,32);
    }
    wsum[h] += __shfl_xor(wsum[h],32);
  }
  __syncthreads();   // p_s reads done; reuse-safe for u_red
  if (wid < 8 && lane < 32){
    #pragma unroll
    for(int h=0;h<4;h++){
      float4 a; a.x=u2[h][0].x; a.y=u2[h][0].y; a.z=u2[h][1].x; a.w=u2[h][1].y;
      float4 cc; cc.x=u2[h][2].x; cc.y=u2[h][2].y; cc.z=u2[h][3].x; cc.w=u2[h][3].y;
      *reinterpret_cast<float4*>(&u_red[wid][h*256 + cl*8    ]) = a;
      *reinterpret_cast<float4*>(&u_red[wid][h*256 + cl*8 + 4]) = cc;
    }
  }
  if (lane==0){
    #pragma unroll
    for(int h=0;h<4;h++) ws_red[wid][h] = wsum[h];
  }
  __syncthreads();
  if (wid >= 8 && lane < 32){
    #pragma unroll
    for(int h=0;h<4;h++){
      float4 a = *reinterpret_cast<const float4*>(&u_red[wid-8][h*256 + cl*8]);
      float4 cc = *reinterpret_cast<const float4*>(&u_red[wid-8][h*256 + cl*8 + 4]);
      a.x+=u2[h][0].x; a.y+=u2[h][0].y; a.z+=u2[h][1].x; a.w+=u2[h][1].y;
      cc.x+=u2[h][2].x; cc.y+=u2[h][2].y; cc.z+=u2[h][3].x; cc.w+=u2[h][3].y;
      *reinterpret_cast<float4*>(&u_red[wid-8][h*256 + cl*8    ]) = a;
      *reinterpret_cast<float4*>(&u_red[wid-8][h*256 + cl*8 + 4]) = cc;
    }
  }
  __syncthreads();
  {
    float sm = 0.f;
    #pragma unroll
    for(int w=0;w<8;w++) sm += u_red[w][tid];
    u_out[((size_t)split*128 + b)*1024 + tid] = sm;
  }
  if (tid < 4){
    float sm = 0.f;
    #pragma unroll
    for(int w=0;w<16;w++) sm += ws_red[w][tid];
    ws_out[((size_t)split*128 + b)*4 + tid] = sm;
  }
}

// ---------------- final step: u4 -> rep_out(d_out), wsum_tot --------------
__global__ __launch_bounds__(1024) void k_finstep(
    const float* __restrict__ u_in, const float* __restrict__ ws_in,
    const float* __restrict__ rep_in,
    const unsigned short* __restrict__ Wvp, const unsigned short* __restrict__ Wip,
    const unsigned short* __restrict__ Whp, const float* __restrict__ bih,
    const float* __restrict__ bhh, const float* __restrict__ ln_rg,
    const float* __restrict__ ln_rb, const unsigned short* __restrict__ W1p,
    const unsigned short* __restrict__ W2p, const float* __restrict__ b2,
    float* __restrict__ out_rep, float* __restrict__ wsum_tot){
  __shared__ float u_s[1024];
  __shared__ float att_s[256], rep_s[256], ln_s[256], nw_s[256];
  __shared__ float gi_s[768], gh_s[768];
  __shared__ float h1_s[1024], red_a[1024];
  __shared__ float ws_s[4]; __shared__ float s16[16];
  int b = blockIdx.x;
  int tid = threadIdx.x;
  int c = tid & 255, s = tid >> 8;
  {
    u_s[tid] = u_in[(size_t)b*1024 + tid] + u_in[((size_t)128 + b)*1024 + tid];
    if (tid < 4){
      float w = ws_in[b*4 + tid] + ws_in[(128 + b)*4 + tid];
      ws_s[tid] = w; wsum_tot[b*4 + tid] = w;
    }
    if (tid < 256) rep_s[tid] = rep_in[b*256 + tid];
  }
  __syncthreads();
  {
    const float* uh = u_s + (c>>6)*256;
    float a = 0.f;
    for(int pk=s*16; pk<s*16+16; ++pk){
      ushort4_t w4 = *reinterpret_cast<const ushort4_t*>(Wvp + ((size_t)pk*256 + c)*4);
      a += bf2f(w4.x)*uh[4*pk] + bf2f(w4.y)*uh[4*pk+1]
         + bf2f(w4.z)*uh[4*pk+2] + bf2f(w4.w)*uh[4*pk+3];
    }
    red_a[tid] = a;
  }
  __syncthreads();
  if (tid < 256) att_s[tid] = (red_a[tid]+red_a[256+tid]+red_a[512+tid]+red_a[768+tid]) / ws_s[tid>>6];
  __syncthreads();
  if (tid < 768){
    float gi=0.f, gh=0.f;
    for(int pk=0;pk<64;++pk){
      ushort4_t wi = *reinterpret_cast<const ushort4_t*>(Wip + ((size_t)pk*768 + tid)*4);
      ushort4_t wh = *reinterpret_cast<const ushort4_t*>(Whp + ((size_t)pk*768 + tid)*4);
      gi += bf2f(wi.x)*att_s[4*pk] + bf2f(wi.y)*att_s[4*pk+1]
          + bf2f(wi.z)*att_s[4*pk+2] + bf2f(wi.w)*att_s[4*pk+3];
      gh += bf2f(wh.x)*rep_s[4*pk] + bf2f(wh.y)*rep_s[4*pk+1]
          + bf2f(wh.z)*rep_s[4*pk+2] + bf2f(wh.w)*rep_s[4*pk+3];
    }
    gi_s[tid] = gi + bih[tid];
    gh_s[tid] = gh + bhh[tid];
  }
  __syncthreads();
  if (tid < 256){
    float rr = sigm(gi_s[tid]     + gh_s[tid]);
    float zz = sigm(gi_s[256+tid] + gh_s[256+tid]);
    float t3 = tanhf(gi_s[512+tid] + rr*gh_s[512+tid]);
    nw_s[tid] = (1.f-zz)*t3 + zz*rep_s[tid];
  }
  __syncthreads();
  {
    float v = nw_s[c];
    float mu = blkSum16(v, s16)*(1.0f/1024.0f);
    float df = v - mu;
    float var = blkSum16(df*df, s16)*(1.0f/1024.0f);
    float rs = rsqrtf(var+1e-5f);
    if (s==0) ln_s[c] = df*rs*ln_rg[c]+ln_rb[c];
  }
  __syncthreads();
  {
    float a = 0.f;
    for(int pk=0;pk<64;++pk){
      ushort4_t w4 = *reinterpret_cast<const ushort4_t*>(W1p + ((size_t)pk*1024 + tid)*4);
      a += bf2f(w4.x)*ln_s[4*pk] + bf2f(w4.y)*ln_s[4*pk+1]
         + bf2f(w4.z)*ln_s[4*pk+2] + bf2f(w4.w)*ln_s[4*pk+3];
    }
    h1_s[tid] = fmaxf(a, 0.f);
  }
  __syncthreads();
  {
    float a = 0.f;
    for(int pk=s*64; pk<s*64+64; ++pk){
      ushort4_t w4 = *reinterpret_cast<const ushort4_t*>(W2p + ((size_t)pk*256 + c)*4);
      a += bf2f(w4.x)*h1_s[4*pk] + bf2f(w4.y)*h1_s[4*pk+1]
         + bf2f(w4.z)*h1_s[4*pk+2] + bf2f(w4.w)*h1_s[4*pk+3];
    }
    red_a[tid] = a;
  }
  __syncthreads();
  if (tid < 256){
    float rn = nw_s[tid] + (red_a[tid]+red_a[256+tid]+red_a[512+tid]+red_a[768+tid]) + b2[tid];
    out_rep[b*256+tid] = rn;
  }
}

// ---------------- final w output ------------------------------------------
__global__ __launch_bounds__(256) void k_wout(
    const float* __restrict__ w_buf, const float* __restrict__ wsum_tot,
    float* __restrict__ out){
  int idx = blockIdx.x*256 + threadIdx.x;     // 0..524287
  int b = idx>>12;
  float4 w4 = *reinterpret_cast<const float4*>(w_buf + (size_t)idx*4);
  out[idx] = w4.x/wsum_tot[b*4+0] + w4.y/wsum_tot[b*4+1]
           + w4.z/wsum_tot[b*4+2] + w4.w/wsum_tot[b*4+3];
}

extern "C" void kernel_launch(void* const* d_in, const int* in_sizes, int n_in,
                              void* d_out, int out_size, void* d_ws, size_t ws_size,
                              hipStream_t stream){
  const float* inputs  = (const float*)d_in[0];
  const float* eps     = (const float*)d_in[1];
  const float* init_mu = (const float*)d_in[2];
  const float* init_lv = (const float*)d_in[3];
  const float* Wk      = (const float*)d_in[4];
  const float* Wv      = (const float*)d_in[5];
  const float* Wq      = (const float*)d_in[6];
  const float* ln_in_g = (const float*)d_in[7];
  const float* ln_in_b = (const float*)d_in[8];
  const float* ln_sg   = (const float*)d_in[9];
  const float* ln_sb   = (const float*)d_in[10];
  const float* ln_rg   = (const float*)d_in[11];
  const float* ln_rb   = (const float*)d_in[12];
  const float* Wih     = (const float*)d_in[13];
  const float* Whh     = (const float*)d_in[14];
  const float* bih     = (const float*)d_in[15];
  const float* bhh     = (const float*)d_in[16];
  const float* W1      = (const float*)d_in[17];
  const float* W2      = (const float*)d_in[18];
  const float* b2      = (const float*)d_in[19];

  char* ws = (char*)d_ws;
  size_t off = 0;
  auto alloc = [&](size_t bytes)->void*{
    void* p = ws + off; off += (bytes + 255) & ~(size_t)255; return p;
  };
  unsigned short* x   = (unsigned short*)alloc((size_t)128*N_*256*2);
  unsigned short* Wvp = (unsigned short*)alloc(65536*2);
  unsigned short* Wip = (unsigned short*)alloc(196608*2);
  unsigned short* Whp = (unsigned short*)alloc(196608*2);
  unsigned short* W1p = (unsigned short*)alloc(262144*2);
  unsigned short* W2p = (unsigned short*)alloc(262144*2);
  unsigned short* Wqp = (unsigned short*)alloc(65536*2);
  unsigned short* Wkp = (unsigned short*)alloc(65536*2);
  float* p0    = (float*)alloc((size_t)128*1024*4);
  float* uA    = (float*)alloc((size_t)2*128*1024*4);
  float* uB    = (float*)alloc((size_t)2*128*1024*4);
  float* wsA   = (float*)alloc(2*128*4*4);
  float* wsB   = (float*)alloc(2*128*4*4);
  float* repA  = (float*)alloc(128*256*4);
  float* repB  = (float*)alloc(128*256*4);
  float* wsum_tot = (float*)alloc(512*4);
  float* w_buf = (float*)alloc((size_t)128*N_*4*4);

  float* out_rep = (float*)d_out;
  float* out_w   = out_rep + 128*256;

  k_prep<<<1024,256,0,stream>>>(Wv,Wih,Whh,W1,W2,Wq,Wk, Wvp,Wip,Whp,W1p,W2p,Wqp,Wkp);
  k_init<<<128,256,0,stream>>>(eps, init_mu, init_lv, ln_sg, ln_sb, Wq, Wkp, repA, p0);
  k_lnattn<<<dim3(2,128),1024,0,stream>>>(inputs, ln_in_g, ln_in_b, p0, x, uA, wsA);
  // t=1: uA->uB, repA->repB
  k_attnstep<<<dim3(2,128),1024,0,stream>>>(x, uA, wsA, repA, repB,
      Wvp,Wip,Whp,bih,bhh,ln_rg,ln_rb,W1p,W2p,b2,ln_sg,ln_sb,Wqp,Wkp,
      uB, wsB, w_buf, 0);
  // t=2: uB->uA, repB->repA
  k_attnstep<<<dim3(2,128),1024,0,stream>>>(x, uB, wsB, repB, repA,
      Wvp,Wip,Whp,bih,bhh,ln_rg,ln_rb,W1p,W2p,b2,ln_sg,ln_sb,Wqp,Wkp,
      uA, wsA, w_buf, 0);
  // t=3: uA->uB, repA->repB, write raw w
  k_attnstep<<<dim3(2,128),1024,0,stream>>>(x, uA, wsA, repA, repB,
      Wvp,Wip,Whp,bih,bhh,ln_rg,ln_rb,W1p,W2p,b2,ln_sg,ln_sb,Wqp,Wkp,
      uB, wsB, w_buf, 1);
  // final step: uB + repB -> out_rep, wsum_tot
  k_finstep<<<128,1024,0,stream>>>(uB, wsB, repB,
      Wvp,Wip,Whp,bih,bhh,ln_rg,ln_rb,W1p,W2p,b2, out_rep, wsum_tot);
  k_wout<<<2048,256,0,stream>>>(w_buf, wsum_tot, out_w);
}